// Round 6
// baseline (8469.329 us; speedup 1.0000x reference)
//
#include <hip/hip_runtime.h>

#define NTOK 262144L

typedef __attribute__((ext_vector_type(4))) float f32x4;
typedef __attribute__((ext_vector_type(8))) short bf16x8;   // 8 x bf16 (4 VGPRs)

static __device__ __forceinline__ unsigned short f2bf(float f) {
  unsigned int u = __builtin_bit_cast(unsigned int, f);
  u += 0x7fffu + ((u >> 16) & 1u);          // round-nearest-even
  return (unsigned short)(u >> 16);
}

static __device__ __forceinline__ unsigned cvtpk(float lo, float hi) {
  unsigned r;
  asm("v_cvt_pk_bf16_f32 %0, %1, %2" : "=v"(r) : "v"(lo), "v"(hi));
  return r;
}

union U8 { unsigned u[4]; bf16x8 v; };

// async global->LDS, 16B per lane; dest is wave-uniform base (HW adds lane*16)
static __device__ __forceinline__ void dma16(const float* gsrc, void* ldst) {
  __builtin_amdgcn_global_load_lds(
      (const __attribute__((address_space(1))) unsigned int*)gsrc,
      (__attribute__((address_space(3))) unsigned int*)ldst, 16, 0, 0);
}

// X (fp32, 512B rows = 32 x 16B slots): slot = c16 ^ sigx(row) -> A-frag reads 2-way max
static __device__ __forceinline__ int sigx(int row) {
  return (row & 1) | ((row & 8) >> 2) | ((row & 6) << 2);
}
// H (bf16, 256B rows = 16 x 16B slots): byte-XOR key
static __device__ __forceinline__ int swzh(int row) {
  return ((row & 8) << 1) | ((row & 6) << 5);
}

// ---- pre-pack all weights fp32 -> bf16 in MFMA B-fragment order ----
__global__ void pack_w(const float* __restrict__ Wt1, const float* __restrict__ Wa1,
                       const float* __restrict__ Wv1, const float* __restrict__ Wt2,
                       const float* __restrict__ Wa2, const float* __restrict__ Wv2,
                       unsigned short* __restrict__ pk) {
  int idx = blockIdx.x * 256 + threadIdx.x;
  if (idx >= 245760) return;
  float v;
  if (idx < 196608) {
    int j = idx & 7, l = (idx >> 3) & 63, ct = (idx >> 9) & 7, kt = (idx >> 12) & 15, e = idx >> 16;
    const float* W = (e == 0) ? Wt1 : (e == 1) ? Wa1 : Wv1;
    v = W[(kt * 32 + ((l >> 4) * 8) + j) * 128 + ct * 16 + (l & 15)];
  } else {
    int i2 = idx - 196608;
    int j = i2 & 7, l = (i2 >> 3) & 63, ct = (i2 >> 9) & 7, kt = (i2 >> 12) & 3, e = i2 >> 14;
    const float* W = (e == 0) ? Wt2 : (e == 1) ? Wa2 : Wv2;
    v = W[(kt * 32 + ((l >> 4) * 8) + j) * 128 + ct * 16 + (l & 15)];
  }
  pk[idx] = f2bf(v);
}

static __device__ __forceinline__ bf16x8 ldA(const char* xb, int row, int ktl, int g) {
  int swz = sigx(row) << 4;
  int base = row * 512 + ktl * 128 + g * 32;
  f32x4 f0 = *(const f32x4*)(xb + (base ^ swz));
  f32x4 f1 = *(const f32x4*)(xb + ((base + 16) ^ swz));
  U8 r;
  r.u[0] = cvtpk(f0[0], f0[1]);
  r.u[1] = cvtpk(f0[2], f0[3]);
  r.u[2] = cvtpk(f1[0], f1[1]);
  r.u[3] = cvtpk(f1[2], f1[3]);
  return r.v;
}

static __device__ __forceinline__ void stH(char* Hb, int g, int col, int rbase, f32x4 a) {
  #pragma unroll
  for (int rp = 0; rp < 2; ++rp) {
    int r0 = rbase + 4 * g + 2 * rp;
    unsigned p = cvtpk(fmaxf(a[2 * rp], 0.f), fmaxf(a[2 * rp + 1], 0.f));
    int a0 = r0 * 256 + ((((col >> 3) << 4)) ^ swzh(r0)) + (col & 7) * 2;
    int a1 = (r0 + 1) * 256 + ((((col >> 3) << 4)) ^ swzh(r0 + 1)) + (col & 7) * 2;
    *(unsigned short*)(Hb + a0) = (unsigned short)p;
    *(unsigned short*)(Hb + a1) = (unsigned short)(p >> 16);
  }
}

static __device__ __forceinline__ bf16x8 ldH(const char* hb, int row, int kt, int g) {
  return *(const bf16x8*)(hb + row * 256 + ((((kt * 4 + g) << 4)) ^ swzh(row)));
}

struct WF { bf16x8 t0, t1, a0, a1, v0, v1; };
static __device__ __forceinline__ WF ldW1(const unsigned short* __restrict__ pk,
                                          int kt, int w, int lane) {
  const int wo = ((kt * 8 + 2 * w) << 9) + (lane << 3);
  WF f;
  f.t0 = *(const bf16x8*)(pk + wo);
  f.t1 = *(const bf16x8*)(pk + wo + 512);
  f.a0 = *(const bf16x8*)(pk + 65536 + wo);
  f.a1 = *(const bf16x8*)(pk + 65536 + wo + 512);
  f.v0 = *(const bf16x8*)(pk + 131072 + wo);
  f.v1 = *(const bf16x8*)(pk + 131072 + wo + 512);
  return f;
}

// ABL: 0=real(d_out,1rep) 1=full 2=noW 3=noX 4=noBAR 5=weight-prefetch (1..5: d_ws, 5 reps)
template <int ABL>
__global__ __launch_bounds__(256, 4) void mlp3(
    const float* __restrict__ X, const unsigned short* __restrict__ pk,
    const float* __restrict__ bt1, const float* __restrict__ bt2,
    const float* __restrict__ ba1, const float* __restrict__ ba2,
    const float* __restrict__ bv1, const float* __restrict__ bv2,
    float* __restrict__ ob) {
  __shared__ float Xs[2 * 32 * 128];            // 32 KiB dbuf (DMA target)
  __shared__ unsigned short H0[32 * 128];       // 8 KiB
  __shared__ unsigned short H1[32 * 128];       // 8 KiB
  const int t = threadIdx.x;
  const long brow = (long)blockIdx.x * 32;
  const int lane = t & 63;
  const int w = t >> 6;
  const int l15 = lane & 15;
  const int g = lane >> 4;
  const float* __restrict__ Xrow = X + brow * 512;

  constexpr int REP = (ABL == 0) ? 1 : 5;
  for (int rep = 0; rep < REP; ++rep) {

    f32x4 at[2][2], aa[2][2], av[2][2];
    #pragma unroll
    for (int c = 0; c < 2; ++c) {
      float b0 = bt1[(2 * w + c) * 16 + l15];
      float b1v = ba1[(2 * w + c) * 16 + l15];
      float b2v = bv1[(2 * w + c) * 16 + l15];
      #pragma unroll
      for (int rt = 0; rt < 2; ++rt) {
        at[rt][c] = (f32x4){b0, b0, b0, b0};
        aa[rt][c] = (f32x4){b1v, b1v, b1v, b1v};
        av[rt][c] = (f32x4){b2v, b2v, b2v, b2v};
      }
    }

    // ---- DMA chunk 0 (and chunk 1 for noX so buf1 is deterministic) ----
    #pragma unroll
    for (int i = 0; i < 4; ++i) {
      int lin = i * 256 + t;
      int row = lin >> 5, S = lin & 31;
      dma16(Xrow + row * 512 + ((S ^ sigx(row)) << 2),
            (char*)Xs + i * 4096 + w * 1024);
      if constexpr (ABL == 3)
        dma16(Xrow + row * 512 + 128 + ((S ^ sigx(row)) << 2),
              (char*)Xs + 16384 + i * 4096 + w * 1024);
    }
    __syncthreads();   // kept in ALL variants (chunk-0 ready)

    unsigned fmask = 0;

    WF cf;
    if constexpr (ABL == 2 || ABL == 5) cf = ldW1(pk, 0, w, lane);

    #pragma unroll
    for (int kc = 0; kc < 4; ++kc) {
      if constexpr (ABL != 3) {
        if (kc < 3) {
          #pragma unroll
          for (int i = 0; i < 4; ++i) {
            int lin = i * 256 + t;
            int row = lin >> 5, S = lin & 31;
            dma16(Xrow + row * 512 + (kc + 1) * 128 + ((S ^ sigx(row)) << 2),
                  (char*)Xs + ((kc + 1) & 1) * 16384 + i * 4096 + w * 1024);
          }
        }
      }
      const char* xb = (ABL == 3) ? (const char*)Xs
                                  : (const char*)Xs + (kc & 1) * 16384;
      __builtin_amdgcn_s_setprio(1);
      #pragma unroll
      for (int ktl = 0; ktl < 4; ++ktl) {
        const int kt = kc * 4 + ktl;
        WF f;
        if constexpr (ABL == 2) {
          f = cf;
        } else if constexpr (ABL == 5) {
          f = cf;
          if (kt < 15) cf = ldW1(pk, kt + 1, w, lane);   // prefetch next kt
        } else {
          f = ldW1(pk, kt, w, lane);
        }
        #pragma unroll
        for (int rt = 0; rt < 2; ++rt) {
          bf16x8 a = ldA(xb, rt * 16 + l15, ktl, g);
          at[rt][0] = __builtin_amdgcn_mfma_f32_16x16x32_bf16(a, f.t0, at[rt][0], 0, 0, 0);
          at[rt][1] = __builtin_amdgcn_mfma_f32_16x16x32_bf16(a, f.t1, at[rt][1], 0, 0, 0);
          aa[rt][0] = __builtin_amdgcn_mfma_f32_16x16x32_bf16(a, f.a0, aa[rt][0], 0, 0, 0);
          aa[rt][1] = __builtin_amdgcn_mfma_f32_16x16x32_bf16(a, f.a1, aa[rt][1], 0, 0, 0);
          av[rt][0] = __builtin_amdgcn_mfma_f32_16x16x32_bf16(a, f.v0, av[rt][0], 0, 0, 0);
          av[rt][1] = __builtin_amdgcn_mfma_f32_16x16x32_bf16(a, f.v1, av[rt][1], 0, 0, 0);
        }
      }
      __builtin_amdgcn_s_setprio(0);
      if (kc == 3) {
        const char* fb = (ABL == 3) ? (const char*)Xs : (const char*)Xs + 16384;
        #pragma unroll
        for (int rt = 0; rt < 2; ++rt)
          #pragma unroll
          for (int r = 0; r < 4; ++r) {
            int row = rt * 16 + 4 * g + r;
            float fv = *(const float*)(fb + row * 512 + (((31 ^ sigx(row)) << 4)) + 12);
            if (fv != 0.f) fmask |= 1u << (rt * 4 + r);
          }
      }
      if (kc < 3) { if constexpr (ABL != 4) __syncthreads(); }
    }

    // ---- relu + hidden tiles ----
    #pragma unroll
    for (int rt = 0; rt < 2; ++rt)
      #pragma unroll
      for (int c = 0; c < 2; ++c) {
        int col = (2 * w + c) * 16 + l15;
        stH((char*)H0, g, col, rt * 16, at[rt][c]);
        stH((char*)H1, g, col, rt * 16, aa[rt][c]);
      }
    if constexpr (ABL != 4) __syncthreads();

    auto layer2 = [&](const unsigned short* Hb, int e, const float* __restrict__ b2,
                      f32x4 a2[2][2]) {
      #pragma unroll
      for (int c = 0; c < 2; ++c) {
        float bv = b2[(2 * w + c) * 16 + l15];
        a2[0][c] = (f32x4){bv, bv, bv, bv};
        a2[1][c] = (f32x4){bv, bv, bv, bv};
      }
      const unsigned short* W2f = pk + 196608 + e * 16384;
      __builtin_amdgcn_s_setprio(1);
      #pragma unroll
      for (int kt = 0; kt < 4; ++kt) {
        int wo = ((kt * 8 + 2 * w) << 9) + (lane << 3);
        bf16x8 w0 = *(const bf16x8*)(W2f + wo);
        bf16x8 w1 = *(const bf16x8*)(W2f + wo + 512);
        #pragma unroll
        for (int rt = 0; rt < 2; ++rt) {
          bf16x8 a = ldH((const char*)Hb, rt * 16 + l15, kt, g);
          a2[rt][0] = __builtin_amdgcn_mfma_f32_16x16x32_bf16(a, w0, a2[rt][0], 0, 0, 0);
          a2[rt][1] = __builtin_amdgcn_mfma_f32_16x16x32_bf16(a, w1, a2[rt][1], 0, 0, 0);
        }
      }
      __builtin_amdgcn_s_setprio(0);
    };

    f32x4 keep[2][2], a2[2][2];
    layer2(H0, 0, bt2, keep);
    layer2(H1, 1, ba2, a2);
    #pragma unroll
    for (int rt = 0; rt < 2; ++rt)
      #pragma unroll
      for (int c = 0; c < 2; ++c)
        #pragma unroll
        for (int r = 0; r < 4; ++r)
          if ((fmask >> (rt * 4 + r)) & 1u) keep[rt][c][r] = a2[rt][c][r];
    if constexpr (ABL != 4) __syncthreads();

    #pragma unroll
    for (int rt = 0; rt < 2; ++rt)
      #pragma unroll
      for (int c = 0; c < 2; ++c) {
        int col = (2 * w + c) * 16 + l15;
        stH((char*)H0, g, col, rt * 16, av[rt][c]);
      }
    if constexpr (ABL != 4) __syncthreads();
    layer2(H0, 2, bv2, a2);

    float* __restrict__ ov = ob + NTOK * 128;
    #pragma unroll
    for (int rt = 0; rt < 2; ++rt)
      #pragma unroll
      for (int c = 0; c < 2; ++c)
        #pragma unroll
        for (int r = 0; r < 4; ++r) {
          long row = brow + rt * 16 + 4 * g + r;
          long col = (2 * w + c) * 16 + l15;
          ob[row * 128 + col] = keep[rt][c][r];
          ov[row * 128 + col] = fmaxf(a2[rt][c][r], 0.f);
        }

    if constexpr (ABL != 4) __syncthreads();   // inter-rep separation (ablations only)
  }
}

extern "C" void kernel_launch(void* const* d_in, const int* in_sizes, int n_in,
                              void* d_out, int out_size, void* d_ws, size_t ws_size,
                              hipStream_t stream) {
  const float* X   = (const float*)d_in[0];
  const float* Wt1 = (const float*)d_in[1];
  const float* bt1 = (const float*)d_in[2];
  const float* Wt2 = (const float*)d_in[3];
  const float* bt2 = (const float*)d_in[4];
  const float* Wa1 = (const float*)d_in[5];
  const float* ba1 = (const float*)d_in[6];
  const float* Wa2 = (const float*)d_in[7];
  const float* ba2 = (const float*)d_in[8];
  const float* Wv1 = (const float*)d_in[9];
  const float* bv1 = (const float*)d_in[10];
  const float* Wv2 = (const float*)d_in[11];
  const float* bv2 = (const float*)d_in[12];
  unsigned short* pk = (unsigned short*)d_ws;   // 480 KiB packed weights

  pack_w<<<960, 256, 0, stream>>>(Wt1, Wa1, Wv1, Wt2, Wa2, Wv2, pk);
  mlp3<0><<<8192, 256, 0, stream>>>(X, pk, bt1, bt2, ba1, ba2, bv1, bv2, (float*)d_out);

  // ---- diagnostic ablations (write only to d_ws; per-dispatch rows in rocprof) ----
  if (ws_size >= ((size_t)400 << 20)) {
    float* ao = (float*)((char*)d_ws + ((size_t)64 << 20));
    mlp3<1><<<8192, 256, 0, stream>>>(X, pk, bt1, bt2, ba1, ba2, bv1, bv2, ao);  // full x5
    mlp3<2><<<8192, 256, 0, stream>>>(X, pk, bt1, bt2, ba1, ba2, bv1, bv2, ao);  // noW  x5
    mlp3<3><<<8192, 256, 0, stream>>>(X, pk, bt1, bt2, ba1, ba2, bv1, bv2, ao);  // noX  x5
    mlp3<4><<<8192, 256, 0, stream>>>(X, pk, bt1, bt2, ba1, ba2, bv1, bv2, ao);  // noBAR x5
    mlp3<5><<<8192, 256, 0, stream>>>(X, pk, bt1, bt2, ba1, ba2, bv1, bv2, ao);  // wpf  x5
  }
}

// Round 7
// 489.098 us; speedup vs baseline: 17.3162x; 17.3162x over previous
//
#include <hip/hip_runtime.h>

#define NTOK 262144L

typedef __attribute__((ext_vector_type(4))) float f32x4;
typedef __attribute__((ext_vector_type(8))) short bf16x8;   // 8 x bf16 (4 VGPRs)

static __device__ __forceinline__ unsigned short f2bf(float f) {
  unsigned int u = __builtin_bit_cast(unsigned int, f);
  u += 0x7fffu + ((u >> 16) & 1u);          // round-nearest-even
  return (unsigned short)(u >> 16);
}

static __device__ __forceinline__ unsigned cvtpk(float lo, float hi) {
  unsigned r;
  asm("v_cvt_pk_bf16_f32 %0, %1, %2" : "=v"(r) : "v"(lo), "v"(hi));
  return r;
}

union U8 { unsigned u[4]; bf16x8 v; };

// H (bf16, 256B rows = 16 x 16B slots): byte-XOR swizzle key
static __device__ __forceinline__ int swzh(int row) {
  return ((row & 8) << 1) | ((row & 6) << 5);
}

// ---- pre-pack all weights fp32 -> bf16 in MFMA B-fragment order ----
// W1 region: [e][kt=16][ct=8][lane=64][j=8]  (k = kt*32 + (lane>>4)*8 + j, col = ct*16 + (lane&15))
// W2 region: [e][kt=4 ][ct=8][lane=64][j=8]
__global__ void pack_w(const float* __restrict__ Wt1, const float* __restrict__ Wa1,
                       const float* __restrict__ Wv1, const float* __restrict__ Wt2,
                       const float* __restrict__ Wa2, const float* __restrict__ Wv2,
                       unsigned short* __restrict__ pk) {
  int idx = blockIdx.x * 256 + threadIdx.x;
  if (idx >= 245760) return;
  float v;
  if (idx < 196608) {
    int j = idx & 7, l = (idx >> 3) & 63, ct = (idx >> 9) & 7, kt = (idx >> 12) & 15, e = idx >> 16;
    const float* W = (e == 0) ? Wt1 : (e == 1) ? Wa1 : Wv1;
    v = W[(kt * 32 + ((l >> 4) * 8) + j) * 128 + ct * 16 + (l & 15)];
  } else {
    int i2 = idx - 196608;
    int j = i2 & 7, l = (i2 >> 3) & 63, ct = (i2 >> 9) & 7, kt = (i2 >> 12) & 3, e = i2 >> 14;
    const float* W = (e == 0) ? Wt2 : (e == 1) ? Wa2 : Wv2;
    v = W[(kt * 32 + ((l >> 4) * 8) + j) * 128 + ct * 16 + (l & 15)];
  }
  pk[idx] = f2bf(v);
}

// store relu(acc) (4 rows 4g..4g+3, one col) into swizzled bf16 H tile
static __device__ __forceinline__ void stH(char* Hb, int g, int col, int rbase, f32x4 a) {
  #pragma unroll
  for (int rp = 0; rp < 2; ++rp) {
    int r0 = rbase + 4 * g + 2 * rp;
    unsigned p = cvtpk(fmaxf(a[2 * rp], 0.f), fmaxf(a[2 * rp + 1], 0.f));
    int a0 = r0 * 256 + ((((col >> 3) << 4)) ^ swzh(r0)) + (col & 7) * 2;
    int a1 = (r0 + 1) * 256 + ((((col >> 3) << 4)) ^ swzh(r0 + 1)) + (col & 7) * 2;
    *(unsigned short*)(Hb + a0) = (unsigned short)p;
    *(unsigned short*)(Hb + a1) = (unsigned short)(p >> 16);
  }
}

static __device__ __forceinline__ bf16x8 ldH(const char* hb, int row, int kt, int g) {
  return *(const bf16x8*)(hb + row * 256 + ((((kt * 4 + g) << 4)) ^ swzh(row)));
}

// Block: 32 rows x 128 cols, 256 thr (4 waves, wave w -> cols [32w, 32w+32)).
// Layer 1 is BARRIER-FREE: A-fragments are loaded directly from global X
// (row = rt*16 + l15, 32 contiguous bytes at imm offset kt*128), weights from
// packed L2-resident pk. Exactly ONE __syncthreads per block (H redistribution).
__global__ __launch_bounds__(256, 4) void mlp3(
    const float* __restrict__ X, const unsigned short* __restrict__ pk,
    const float* __restrict__ bt1, const float* __restrict__ bt2,
    const float* __restrict__ ba1, const float* __restrict__ ba2,
    const float* __restrict__ bv1, const float* __restrict__ bv2,
    float* __restrict__ out) {
  __shared__ unsigned short H0[32 * 128];   // 8 KiB
  __shared__ unsigned short H1[32 * 128];   // 8 KiB
  __shared__ unsigned short H2[32 * 128];   // 8 KiB
  const int t = threadIdx.x;
  const long brow = (long)blockIdx.x * 32;
  const int lane = t & 63;
  const int w = t >> 6;
  const int l15 = lane & 15;
  const int g = lane >> 4;

  // per-lane A-operand base: row brow + l15 (+16 for rt=1), k-offset g*8
  const float* __restrict__ A0 = X + (brow + l15) * 512 + g * 8;

  // routing flags, read directly from global (col 511); issued early
  float flg[8];
  #pragma unroll
  for (int rt = 0; rt < 2; ++rt)
    #pragma unroll
    for (int r = 0; r < 4; ++r)
      flg[rt * 4 + r] = X[(brow + rt * 16 + 4 * g + r) * 512 + 511];

  // ---- layer-1 accumulators, 3 experts ----
  f32x4 at[2][2], aa[2][2], av[2][2];
  #pragma unroll
  for (int c = 0; c < 2; ++c) {
    float b0 = bt1[(2 * w + c) * 16 + l15];
    float b1v = ba1[(2 * w + c) * 16 + l15];
    float b2v = bv1[(2 * w + c) * 16 + l15];
    #pragma unroll
    for (int rt = 0; rt < 2; ++rt) {
      at[rt][c] = (f32x4){b0, b0, b0, b0};
      aa[rt][c] = (f32x4){b1v, b1v, b1v, b1v};
      av[rt][c] = (f32x4){b2v, b2v, b2v, b2v};
    }
  }

  // ---- fused layer-1 K loop: no LDS, no barriers ----
  #pragma unroll 4
  for (int kt = 0; kt < 16; ++kt) {
    bf16x8 afr[2];
    #pragma unroll
    for (int rt = 0; rt < 2; ++rt) {
      const float* p = A0 + rt * (16 * 512) + kt * 32;
      f32x4 f0 = *(const f32x4*)p;
      f32x4 f1 = *(const f32x4*)(p + 4);
      U8 u;
      u.u[0] = cvtpk(f0[0], f0[1]);
      u.u[1] = cvtpk(f0[2], f0[3]);
      u.u[2] = cvtpk(f1[0], f1[1]);
      u.u[3] = cvtpk(f1[2], f1[3]);
      afr[rt] = u.v;
    }
    const int wo = ((kt * 8 + 2 * w) << 9) + (lane << 3);
    bf16x8 wt0 = *(const bf16x8*)(pk + wo);
    bf16x8 wt1v = *(const bf16x8*)(pk + wo + 512);
    bf16x8 wa0 = *(const bf16x8*)(pk + 65536 + wo);
    bf16x8 wa1v = *(const bf16x8*)(pk + 65536 + wo + 512);
    bf16x8 wv0 = *(const bf16x8*)(pk + 131072 + wo);
    bf16x8 wv1v = *(const bf16x8*)(pk + 131072 + wo + 512);
    #pragma unroll
    for (int rt = 0; rt < 2; ++rt) {
      at[rt][0] = __builtin_amdgcn_mfma_f32_16x16x32_bf16(afr[rt], wt0, at[rt][0], 0, 0, 0);
      at[rt][1] = __builtin_amdgcn_mfma_f32_16x16x32_bf16(afr[rt], wt1v, at[rt][1], 0, 0, 0);
      aa[rt][0] = __builtin_amdgcn_mfma_f32_16x16x32_bf16(afr[rt], wa0, aa[rt][0], 0, 0, 0);
      aa[rt][1] = __builtin_amdgcn_mfma_f32_16x16x32_bf16(afr[rt], wa1v, aa[rt][1], 0, 0, 0);
      av[rt][0] = __builtin_amdgcn_mfma_f32_16x16x32_bf16(afr[rt], wv0, av[rt][0], 0, 0, 0);
      av[rt][1] = __builtin_amdgcn_mfma_f32_16x16x32_bf16(afr[rt], wv1v, av[rt][1], 0, 0, 0);
    }
  }

  // ---- relu + write all 3 hidden tiles; the ONLY barrier ----
  #pragma unroll
  for (int rt = 0; rt < 2; ++rt)
    #pragma unroll
    for (int c = 0; c < 2; ++c) {
      int col = (2 * w + c) * 16 + l15;
      stH((char*)H0, g, col, rt * 16, at[rt][c]);
      stH((char*)H1, g, col, rt * 16, aa[rt][c]);
      stH((char*)H2, g, col, rt * 16, av[rt][c]);
    }
  __syncthreads();

  // ---- layer 2 (one expert) ----
  auto layer2 = [&](const unsigned short* Hb, int e, const float* __restrict__ b2,
                    f32x4 a2[2][2]) {
    #pragma unroll
    for (int c = 0; c < 2; ++c) {
      float bv = b2[(2 * w + c) * 16 + l15];
      a2[0][c] = (f32x4){bv, bv, bv, bv};
      a2[1][c] = (f32x4){bv, bv, bv, bv};
    }
    const unsigned short* W2f = pk + 196608 + e * 16384;
    #pragma unroll
    for (int kt = 0; kt < 4; ++kt) {
      int wo = ((kt * 8 + 2 * w) << 9) + (lane << 3);
      bf16x8 w0 = *(const bf16x8*)(W2f + wo);
      bf16x8 w1 = *(const bf16x8*)(W2f + wo + 512);
      #pragma unroll
      for (int rt = 0; rt < 2; ++rt) {
        bf16x8 a = ldH((const char*)Hb, rt * 16 + l15, kt, g);
        a2[rt][0] = __builtin_amdgcn_mfma_f32_16x16x32_bf16(a, w0, a2[rt][0], 0, 0, 0);
        a2[rt][1] = __builtin_amdgcn_mfma_f32_16x16x32_bf16(a, w1, a2[rt][1], 0, 0, 0);
      }
    }
  };

  f32x4 keep[2][2], a2[2][2];
  layer2(H0, 0, bt2, keep);    // transform
  layer2(H1, 1, ba2, a2);      // actor
  #pragma unroll
  for (int rt = 0; rt < 2; ++rt)
    #pragma unroll
    for (int c = 0; c < 2; ++c)
      #pragma unroll
      for (int r = 0; r < 4; ++r)
        if (flg[rt * 4 + r] != 0.f) keep[rt][c][r] = a2[rt][c][r];
  layer2(H2, 2, bv2, a2);      // value

  // ---- batched stores ----
  float* __restrict__ ov = out + NTOK * 128;
  #pragma unroll
  for (int rt = 0; rt < 2; ++rt)
    #pragma unroll
    for (int c = 0; c < 2; ++c)
      #pragma unroll
      for (int r = 0; r < 4; ++r) {
        long row = brow + rt * 16 + 4 * g + r;
        long col = (2 * w + c) * 16 + l15;
        out[row * 128 + col] = keep[rt][c][r];
        ov[row * 128 + col] = fmaxf(a2[rt][c][r], 0.f);
      }
}

extern "C" void kernel_launch(void* const* d_in, const int* in_sizes, int n_in,
                              void* d_out, int out_size, void* d_ws, size_t ws_size,
                              hipStream_t stream) {
  const float* X   = (const float*)d_in[0];
  const float* Wt1 = (const float*)d_in[1];
  const float* bt1 = (const float*)d_in[2];
  const float* Wt2 = (const float*)d_in[3];
  const float* bt2 = (const float*)d_in[4];
  const float* Wa1 = (const float*)d_in[5];
  const float* ba1 = (const float*)d_in[6];
  const float* Wa2 = (const float*)d_in[7];
  const float* ba2 = (const float*)d_in[8];
  const float* Wv1 = (const float*)d_in[9];
  const float* bv1 = (const float*)d_in[10];
  const float* Wv2 = (const float*)d_in[11];
  const float* bv2 = (const float*)d_in[12];
  unsigned short* pk = (unsigned short*)d_ws;   // 245760 bf16 = 480 KiB packed weights

  pack_w<<<960, 256, 0, stream>>>(Wt1, Wa1, Wv1, Wt2, Wa2, Wv2, pk);
  mlp3<<<8192, 256, 0, stream>>>(X, pk, bt1, bt2, ba1, ba2, bv1, bv2, (float*)d_out);
}

// Round 8
// 465.675 us; speedup vs baseline: 18.1872x; 1.0503x over previous
//
#include <hip/hip_runtime.h>

#define NTOK 262144L

typedef __attribute__((ext_vector_type(4))) float f32x4;
typedef __attribute__((ext_vector_type(8))) short bf16x8;   // 8 x bf16 (4 VGPRs)

static __device__ __forceinline__ unsigned short f2bf(float f) {
  unsigned int u = __builtin_bit_cast(unsigned int, f);
  u += 0x7fffu + ((u >> 16) & 1u);          // round-nearest-even
  return (unsigned short)(u >> 16);
}

static __device__ __forceinline__ unsigned cvtpk(float lo, float hi) {
  unsigned r;
  asm("v_cvt_pk_bf16_f32 %0, %1, %2" : "=v"(r) : "v"(lo), "v"(hi));
  return r;
}

union U8 { unsigned u[4]; bf16x8 v; };

// H (bf16, 256B rows = 16 x 16B slots): byte-XOR swizzle key
static __device__ __forceinline__ int swzh(int row) {
  return ((row & 8) << 1) | ((row & 6) << 5);
}

// ---- pre-pack all weights fp32 -> bf16 in MFMA B-fragment order ----
// W1 region: [e][kt=16][ct=8][lane=64][j=8]  (k = kt*32 + (lane>>4)*8 + j, col = ct*16 + (lane&15))
// W2 region: [e][kt=4 ][ct=8][lane=64][j=8]
__global__ void pack_w(const float* __restrict__ Wt1, const float* __restrict__ Wa1,
                       const float* __restrict__ Wv1, const float* __restrict__ Wt2,
                       const float* __restrict__ Wa2, const float* __restrict__ Wv2,
                       unsigned short* __restrict__ pk) {
  int idx = blockIdx.x * 256 + threadIdx.x;
  if (idx >= 245760) return;
  float v;
  if (idx < 196608) {
    int j = idx & 7, l = (idx >> 3) & 63, ct = (idx >> 9) & 7, kt = (idx >> 12) & 15, e = idx >> 16;
    const float* W = (e == 0) ? Wt1 : (e == 1) ? Wa1 : Wv1;
    v = W[(kt * 32 + ((l >> 4) * 8) + j) * 128 + ct * 16 + (l & 15)];
  } else {
    int i2 = idx - 196608;
    int j = i2 & 7, l = (i2 >> 3) & 63, ct = (i2 >> 9) & 7, kt = (i2 >> 12) & 3, e = i2 >> 14;
    const float* W = (e == 0) ? Wt2 : (e == 1) ? Wa2 : Wv2;
    v = W[(kt * 32 + ((l >> 4) * 8) + j) * 128 + ct * 16 + (l & 15)];
  }
  pk[idx] = f2bf(v);
}

// store relu(acc) (4 rows 4g..4g+3, one col) into swizzled bf16 H tile
static __device__ __forceinline__ void stH(char* Hb, int g, int col, int rbase, f32x4 a) {
  #pragma unroll
  for (int rp = 0; rp < 2; ++rp) {
    int r0 = rbase + 4 * g + 2 * rp;
    unsigned p = cvtpk(fmaxf(a[2 * rp], 0.f), fmaxf(a[2 * rp + 1], 0.f));
    int a0 = r0 * 256 + ((((col >> 3) << 4)) ^ swzh(r0)) + (col & 7) * 2;
    int a1 = (r0 + 1) * 256 + ((((col >> 3) << 4)) ^ swzh(r0 + 1)) + (col & 7) * 2;
    *(unsigned short*)(Hb + a0) = (unsigned short)p;
    *(unsigned short*)(Hb + a1) = (unsigned short)(p >> 16);
  }
}

static __device__ __forceinline__ bf16x8 ldH(const char* hb, int row, int kt, int g) {
  return *(const bf16x8*)(hb + row * 256 + ((((kt * 4 + g) << 4)) ^ swzh(row)));
}

struct WF { bf16x8 t0, t1, a0, a1, v0, v1; };
static __device__ __forceinline__ WF ldW1(const unsigned short* __restrict__ pk,
                                          int kt, int w, int lane) {
  const int wo = ((kt * 8 + 2 * w) << 9) + (lane << 3);
  WF f;
  f.t0 = *(const bf16x8*)(pk + wo);
  f.t1 = *(const bf16x8*)(pk + wo + 512);
  f.a0 = *(const bf16x8*)(pk + 65536 + wo);
  f.a1 = *(const bf16x8*)(pk + 65536 + wo + 512);
  f.v0 = *(const bf16x8*)(pk + 131072 + wo);
  f.v1 = *(const bf16x8*)(pk + 131072 + wo + 512);
  return f;
}

// Block: 32 rows x 128 cols, 256 thr (4 waves, wave w -> cols [32w, 32w+32)).
// Layer 1: barrier-free, A direct from global X, W+A software-prefetched 1 kt
// ahead (depth-1 covers L2 latency under the 12-MFMA cluster). ONE barrier.
// amdgpu_waves_per_eu(3,3): pin allocator at 3 waves/EU (<=168 VGPR) so it
// cannot trade registers for occupancy (R5/R6/R7 spill failure mode).
__global__ __launch_bounds__(256) __attribute__((amdgpu_waves_per_eu(3, 3)))
void mlp3(
    const float* __restrict__ X, const unsigned short* __restrict__ pk,
    const float* __restrict__ bt1, const float* __restrict__ bt2,
    const float* __restrict__ ba1, const float* __restrict__ ba2,
    const float* __restrict__ bv1, const float* __restrict__ bv2,
    float* __restrict__ out) {
  __shared__ unsigned short H0[32 * 128];   // 8 KiB
  __shared__ unsigned short H1[32 * 128];   // 8 KiB
  __shared__ unsigned short H2[32 * 128];   // 8 KiB
  const int t = threadIdx.x;
  const long brow = (long)blockIdx.x * 32;
  const int lane = t & 63;
  const int w = t >> 6;
  const int l15 = lane & 15;
  const int g = lane >> 4;

  // per-lane A-operand bases: rows brow+l15 and brow+l15+16, k-offset g*8
  const float* __restrict__ A0 = X + (brow + l15) * 512 + g * 8;
  const float* __restrict__ A1 = A0 + 16 * 512;

  // routing flags (col 511; line already fetched by A-loads)
  float flg[8];
  #pragma unroll
  for (int rt = 0; rt < 2; ++rt)
    #pragma unroll
    for (int r = 0; r < 4; ++r)
      flg[rt * 4 + r] = X[(brow + rt * 16 + 4 * g + r) * 512 + 511];

  // ---- layer-1 accumulators, 3 experts ----
  f32x4 at[2][2], aa[2][2], av[2][2];
  #pragma unroll
  for (int c = 0; c < 2; ++c) {
    float b0 = bt1[(2 * w + c) * 16 + l15];
    float b1v = ba1[(2 * w + c) * 16 + l15];
    float b2v = bv1[(2 * w + c) * 16 + l15];
    #pragma unroll
    for (int rt = 0; rt < 2; ++rt) {
      at[rt][c] = (f32x4){b0, b0, b0, b0};
      aa[rt][c] = (f32x4){b1v, b1v, b1v, b1v};
      av[rt][c] = (f32x4){b2v, b2v, b2v, b2v};
    }
  }

  // ---- prefetch kt=0 ----
  WF wf = ldW1(pk, 0, w, lane);
  f32x4 x0a = *(const f32x4*)(A0);
  f32x4 x0b = *(const f32x4*)(A0 + 4);
  f32x4 x1a = *(const f32x4*)(A1);
  f32x4 x1b = *(const f32x4*)(A1 + 4);

  // ---- fused layer-1 K loop: barrier-free, depth-1 pipeline ----
  #pragma unroll 1
  for (int kt = 0; kt < 16; ++kt) {
    WF f = wf;
    f32x4 c0a = x0a, c0b = x0b, c1a = x1a, c1b = x1b;
    if (kt < 15) {   // issue kt+1's loads before kt's MFMA cluster
      wf = ldW1(pk, kt + 1, w, lane);
      const float* p0 = A0 + (kt + 1) * 32;
      const float* p1 = A1 + (kt + 1) * 32;
      x0a = *(const f32x4*)p0;
      x0b = *(const f32x4*)(p0 + 4);
      x1a = *(const f32x4*)p1;
      x1b = *(const f32x4*)(p1 + 4);
    }
    U8 u0, u1;
    u0.u[0] = cvtpk(c0a[0], c0a[1]);
    u0.u[1] = cvtpk(c0a[2], c0a[3]);
    u0.u[2] = cvtpk(c0b[0], c0b[1]);
    u0.u[3] = cvtpk(c0b[2], c0b[3]);
    u1.u[0] = cvtpk(c1a[0], c1a[1]);
    u1.u[1] = cvtpk(c1a[2], c1a[3]);
    u1.u[2] = cvtpk(c1b[0], c1b[1]);
    u1.u[3] = cvtpk(c1b[2], c1b[3]);
    at[0][0] = __builtin_amdgcn_mfma_f32_16x16x32_bf16(u0.v, f.t0, at[0][0], 0, 0, 0);
    at[0][1] = __builtin_amdgcn_mfma_f32_16x16x32_bf16(u0.v, f.t1, at[0][1], 0, 0, 0);
    aa[0][0] = __builtin_amdgcn_mfma_f32_16x16x32_bf16(u0.v, f.a0, aa[0][0], 0, 0, 0);
    aa[0][1] = __builtin_amdgcn_mfma_f32_16x16x32_bf16(u0.v, f.a1, aa[0][1], 0, 0, 0);
    av[0][0] = __builtin_amdgcn_mfma_f32_16x16x32_bf16(u0.v, f.v0, av[0][0], 0, 0, 0);
    av[0][1] = __builtin_amdgcn_mfma_f32_16x16x32_bf16(u0.v, f.v1, av[0][1], 0, 0, 0);
    at[1][0] = __builtin_amdgcn_mfma_f32_16x16x32_bf16(u1.v, f.t0, at[1][0], 0, 0, 0);
    at[1][1] = __builtin_amdgcn_mfma_f32_16x16x32_bf16(u1.v, f.t1, at[1][1], 0, 0, 0);
    aa[1][0] = __builtin_amdgcn_mfma_f32_16x16x32_bf16(u1.v, f.a0, aa[1][0], 0, 0, 0);
    aa[1][1] = __builtin_amdgcn_mfma_f32_16x16x32_bf16(u1.v, f.a1, aa[1][1], 0, 0, 0);
    av[1][0] = __builtin_amdgcn_mfma_f32_16x16x32_bf16(u1.v, f.v0, av[1][0], 0, 0, 0);
    av[1][1] = __builtin_amdgcn_mfma_f32_16x16x32_bf16(u1.v, f.v1, av[1][1], 0, 0, 0);
  }

  // ---- relu + write all 3 hidden tiles; the ONLY barrier ----
  #pragma unroll
  for (int rt = 0; rt < 2; ++rt)
    #pragma unroll
    for (int c = 0; c < 2; ++c) {
      int col = (2 * w + c) * 16 + l15;
      stH((char*)H0, g, col, rt * 16, at[rt][c]);
      stH((char*)H1, g, col, rt * 16, aa[rt][c]);
      stH((char*)H2, g, col, rt * 16, av[rt][c]);
    }
  __syncthreads();

  // ---- layer 2: all 3 experts in ONE loop (3x ILP, loads overlap MFMAs) ----
  f32x4 k2[2][2], a2[2][2], v2[2][2];
  #pragma unroll
  for (int c = 0; c < 2; ++c) {
    float b0 = bt2[(2 * w + c) * 16 + l15];
    float b1v = ba2[(2 * w + c) * 16 + l15];
    float b2v = bv2[(2 * w + c) * 16 + l15];
    #pragma unroll
    for (int rt = 0; rt < 2; ++rt) {
      k2[rt][c] = (f32x4){b0, b0, b0, b0};
      a2[rt][c] = (f32x4){b1v, b1v, b1v, b1v};
      v2[rt][c] = (f32x4){b2v, b2v, b2v, b2v};
    }
  }
  const unsigned short* __restrict__ W2 = pk + 196608;
  #pragma unroll
  for (int kt = 0; kt < 4; ++kt) {
    const int wo = ((kt * 8 + 2 * w) << 9) + (lane << 3);
    bf16x8 wt0 = *(const bf16x8*)(W2 + wo);
    bf16x8 wt1v = *(const bf16x8*)(W2 + wo + 512);
    bf16x8 wa0 = *(const bf16x8*)(W2 + 16384 + wo);
    bf16x8 wa1v = *(const bf16x8*)(W2 + 16384 + wo + 512);
    bf16x8 wv0 = *(const bf16x8*)(W2 + 32768 + wo);
    bf16x8 wv1v = *(const bf16x8*)(W2 + 32768 + wo + 512);
    #pragma unroll
    for (int rt = 0; rt < 2; ++rt) {
      bf16x8 h0 = ldH((const char*)H0, rt * 16 + l15, kt, g);
      bf16x8 h1 = ldH((const char*)H1, rt * 16 + l15, kt, g);
      bf16x8 h2 = ldH((const char*)H2, rt * 16 + l15, kt, g);
      k2[rt][0] = __builtin_amdgcn_mfma_f32_16x16x32_bf16(h0, wt0, k2[rt][0], 0, 0, 0);
      k2[rt][1] = __builtin_amdgcn_mfma_f32_16x16x32_bf16(h0, wt1v, k2[rt][1], 0, 0, 0);
      a2[rt][0] = __builtin_amdgcn_mfma_f32_16x16x32_bf16(h1, wa0, a2[rt][0], 0, 0, 0);
      a2[rt][1] = __builtin_amdgcn_mfma_f32_16x16x32_bf16(h1, wa1v, a2[rt][1], 0, 0, 0);
      v2[rt][0] = __builtin_amdgcn_mfma_f32_16x16x32_bf16(h2, wv0, v2[rt][0], 0, 0, 0);
      v2[rt][1] = __builtin_amdgcn_mfma_f32_16x16x32_bf16(h2, wv1v, v2[rt][1], 0, 0, 0);
    }
  }

  // ---- select + batched stores ----
  float* __restrict__ ov = out + NTOK * 128;
  #pragma unroll
  for (int rt = 0; rt < 2; ++rt)
    #pragma unroll
    for (int c = 0; c < 2; ++c)
      #pragma unroll
      for (int r = 0; r < 4; ++r) {
        long row = brow + rt * 16 + 4 * g + r;
        long col = (2 * w + c) * 16 + l15;
        float pi = (flg[rt * 4 + r] != 0.f) ? a2[rt][c][r] : k2[rt][c][r];
        out[row * 128 + col] = pi;
        ov[row * 128 + col] = fmaxf(v2[rt][c][r], 0.f);
      }
}

extern "C" void kernel_launch(void* const* d_in, const int* in_sizes, int n_in,
                              void* d_out, int out_size, void* d_ws, size_t ws_size,
                              hipStream_t stream) {
  const float* X   = (const float*)d_in[0];
  const float* Wt1 = (const float*)d_in[1];
  const float* bt1 = (const float*)d_in[2];
  const float* Wt2 = (const float*)d_in[3];
  const float* bt2 = (const float*)d_in[4];
  const float* Wa1 = (const float*)d_in[5];
  const float* ba1 = (const float*)d_in[6];
  const float* Wa2 = (const float*)d_in[7];
  const float* ba2 = (const float*)d_in[8];
  const float* Wv1 = (const float*)d_in[9];
  const float* bv1 = (const float*)d_in[10];
  const float* Wv2 = (const float*)d_in[11];
  const float* bv2 = (const float*)d_in[12];
  unsigned short* pk = (unsigned short*)d_ws;   // 245760 bf16 = 480 KiB packed weights

  pack_w<<<960, 256, 0, stream>>>(Wt1, Wa1, Wv1, Wt2, Wa2, Wv2, pk);
  mlp3<<<8192, 256, 0, stream>>>(X, pk, bt1, bt2, ba1, ba2, bv1, bv2, (float*)d_out);
}